// Round 1
// baseline (6939.289 us; speedup 1.0000x reference)
//
#include <hip/hip_runtime.h>
#include <math.h>

#define Q 2048
#define NOBS 8192
#define NB 64
#define NSTEPS (Q / NB)   // 32

// ---------------------------------------------------------------------------
// block-wide sum, blockDim.x == 256 (4 waves of 64)
__device__ __forceinline__ float block_sum256(float v, volatile float* red) {
  int tid = threadIdx.x;
#pragma unroll
  for (int o = 32; o > 0; o >>= 1) v += __shfl_down(v, o);
  __syncthreads();                       // protect red against previous use
  if ((tid & 63) == 0) red[tid >> 6] = v;
  __syncthreads();
  return red[0] + red[1] + red[2] + red[3];
}

// ---------------------------------------------------------------------------
// Per-observation: m_i = sqrt(2)*erfinv(2*clip(Phi(r/sqrt(sig2)))-1),
// scatter t[z]+=m, n[z]+=1, accumulate sum_log_pdf and m'm.
__global__ __launch_bounds__(256) void obs_kernel(
    const float* __restrict__ yt, const float* __restrict__ yp,
    const int* __restrict__ zidx, const float* __restrict__ s2e_p,
    const float* __restrict__ s2b_p, float* __restrict__ t,
    int* __restrict__ cnt, float* __restrict__ scal) {
  __shared__ float red[4];
  int i = blockIdx.x * 256 + threadIdx.x;
  float s2e = s2e_p[0], s2b = s2b_p[0];
  float sig2 = s2e + s2b;
  float r = yt[i] - yp[i];
  float e = erff(r * rsqrtf(2.0f * sig2));
  float u = 0.5f * (e + 1.0f);
  u = fminf(fmaxf(u, 1e-5f), 1.0f - 1e-5f);
  float m = erfinvf(2.0f * u - 1.0f) * 1.4142135623730951f;
  float slp = -0.5f * logf(2.0f * 3.14159265358979f * sig2) - r * r / (2.0f * sig2);
  int z = zidx[i];
  atomicAdd(&t[z], m);
  atomicAdd(&cnt[z], 1);
  float s1 = block_sum256(slp, red);
  float s2 = block_sum256(m * m, red);
  if (threadIdx.x == 0) {
    atomicAdd(&scal[0], s1);   // sum_log_pdf
    atomicAdd(&scal[1], s2);   // m'm
  }
}

// ---------------------------------------------------------------------------
// G[j,k] = sqrt(n_j n_k) * (s2b/sig2) * exp(-dist/(2*ell)) + c*delta_jk
__global__ __launch_bounds__(256) void build_G(
    const float* __restrict__ dist, const float* __restrict__ s2e_p,
    const float* __restrict__ s2b_p, const float* __restrict__ ell_p,
    const int* __restrict__ cnt, float* __restrict__ G) {
  int idx = blockIdx.x * 256 + threadIdx.x;   // < 2^22, fits int
  int j = idx >> 11;
  int k = idx & (Q - 1);
  float s2e = s2e_p[0], s2b = s2b_p[0], ell = ell_p[0];
  float sig2 = s2e + s2b;
  float a = (s2b / sig2) * expf(-dist[idx] / (2.0f * ell));
  float g = sqrtf((float)cnt[j] * (float)cnt[k]) * a;
  if (j == k) g += s2e / sig2;
  G[idx] = g;
}

// ---------------------------------------------------------------------------
// w = A t  (A recomputed from dist), b = sqrt(n) .* w, tw += t.w
__global__ __launch_bounds__(256) void matvec_kernel(
    const float* __restrict__ dist, const float* __restrict__ s2e_p,
    const float* __restrict__ s2b_p, const float* __restrict__ ell_p,
    const int* __restrict__ cnt, const float* __restrict__ t,
    float* __restrict__ w, float* __restrict__ b, float* __restrict__ scal) {
  __shared__ float red[4];
  int j = blockIdx.x;
  float s2e = s2e_p[0], s2b = s2b_p[0], ell = ell_p[0];
  float sig2 = s2e + s2b;
  float inv2ell = 1.0f / (2.0f * ell);
  float s = 0.0f;
  const float* drow = dist + (size_t)j * Q;
  for (int k = threadIdx.x; k < Q; k += 256) s += expf(-drow[k] * inv2ell) * t[k];
  float tot = block_sum256(s, red);
  if (threadIdx.x == 0) {
    float wj = (s2b / sig2) * tot;
    w[j] = wj;
    b[j] = sqrtf((float)cnt[j]) * wj;
    atomicAdd(&scal[2], t[j] * wj);   // t.w
  }
}

// ---------------------------------------------------------------------------
// Factor 64x64 diagonal block in-place. One wave; row per lane in registers.
__global__ __launch_bounds__(64) void chol_diag(float* __restrict__ G, int j0) {
  int lane = threadIdx.x;
  float* row = G + (size_t)(j0 + lane) * Q + j0;
  float rr[64];
#pragma unroll
  for (int k = 0; k < 64; ++k) rr[k] = row[k];
#pragma unroll
  for (int j = 0; j < 64; ++j) {
    float vjj = __shfl(rr[j], j);        // lane j's updated diagonal
    float invd = rsqrtf(vjj);
    float lij = rr[j] * invd;            // lane j gets sqrt(vjj) automatically
    rr[j] = lij;
#pragma unroll
    for (int k = 0; k < 64; ++k) {
      if (k > j) {
        float lkj = __shfl(lij, k);      // only reads lanes k > j (valid)
        rr[k] -= lij * lkj;
      }
    }
  }
#pragma unroll
  for (int k = 0; k < 64; ++k)
    if (k <= lane) row[k] = rr[k];       // store lower triangle only
}

// ---------------------------------------------------------------------------
// L21 = A21 * L11^{-T}: one wave per row, lane-parallel forward substitution.
__global__ __launch_bounds__(256) void chol_trsm(float* __restrict__ G, int j0) {
  __shared__ float Bs[64][65];
  int tid = threadIdx.x;
  for (int idx = tid; idx < 4096; idx += 256) {
    int r = idx >> 6, c = idx & 63;
    Bs[r][c] = G[(size_t)(j0 + r) * Q + j0 + c];
  }
  __syncthreads();
  int lane = tid & 63, wv = tid >> 6;
  int r = j0 + 64 + blockIdx.x * 4 + wv;
  if (r >= Q) return;
  float* grow = G + (size_t)r * Q + j0;
  float a = grow[lane];
  float invd = 1.0f / Bs[lane][lane];
  for (int p = 0; p < 64; ++p) {
    float xp = __shfl(a, p) * __shfl(invd, p);
    if (lane > p) a -= xp * Bs[lane][p];
  }
  grow[lane] = a * invd;
}

// ---------------------------------------------------------------------------
// Trailing update: G22 -= L21 L21^T, 64x64 tiles, lower triangle of tiles.
__global__ __launch_bounds__(256) void chol_syrk(float* __restrict__ G, int j0) {
  int bk = blockIdx.x, bi = blockIdx.y;
  if (bi < bk) return;                       // uniform per block
  __shared__ float P[64][65], Qs[64][65];
  int R = j0 + 64 + bi * 64, C = j0 + 64 + bk * 64;
  int tid = threadIdx.x;
  for (int idx = tid; idx < 4096; idx += 256) {
    int r = idx >> 6, c = idx & 63;
    P[r][c]  = G[(size_t)(R + r) * Q + j0 + c];
    Qs[r][c] = G[(size_t)(C + r) * Q + j0 + c];
  }
  __syncthreads();
  int tx = tid & 15, ty = tid >> 4;
  float acc[4][4] = {{0.f}};
  for (int p = 0; p < 64; ++p) {
    float av[4], bv[4];
#pragma unroll
    for (int i = 0; i < 4; ++i) av[i] = P[ty * 4 + i][p];
#pragma unroll
    for (int jj = 0; jj < 4; ++jj) bv[jj] = Qs[tx * 4 + jj][p];
#pragma unroll
    for (int i = 0; i < 4; ++i)
#pragma unroll
      for (int jj = 0; jj < 4; ++jj) acc[i][jj] += av[i] * bv[jj];
  }
#pragma unroll
  for (int i = 0; i < 4; ++i)
#pragma unroll
    for (int jj = 0; jj < 4; ++jj)
      G[(size_t)(R + ty * 4 + i) * Q + C + tx * 4 + jj] -= acc[i][jj];
}

// ---------------------------------------------------------------------------
// Forward solve L z = b (blocked), then assemble the final scalar loss.
__global__ __launch_bounds__(256) void trsv_final(
    const float* __restrict__ G, const float* __restrict__ b,
    const float* __restrict__ scal, const float* __restrict__ s2e_p,
    const float* __restrict__ s2b_p, float* __restrict__ out) {
  __shared__ float zs[Q];          // 8 KB
  __shared__ float diag[64][65];   // 16.6 KB
  __shared__ float red[256];
  int tid = threadIdx.x;
  for (int i = tid; i < Q; i += 256) zs[i] = b[i];
  __syncthreads();
  for (int sb = 0; sb < NSTEPS; ++sb) {
    int row0 = sb * 64;
    int rl = tid >> 2, part = tid & 3;
    const float* Lrow = G + (size_t)(row0 + rl) * Q;
    float s = 0.0f;
    for (int p = part; p < row0; p += 4) s += Lrow[p] * zs[p];
    red[tid] = s;
    __syncthreads();
    if (part == 0) {
      float tot = red[tid] + red[tid + 1] + red[tid + 2] + red[tid + 3];
      zs[row0 + rl] -= tot;
    }
    // stage diagonal block (coalesced) for the wave-level solve
    for (int idx = tid; idx < 4096; idx += 256) {
      int r = idx >> 6, c = idx & 63;
      diag[r][c] = G[(size_t)(row0 + r) * Q + row0 + c];
    }
    __syncthreads();
    if (tid < 64) {
      int lane = tid;
      float z = zs[row0 + lane];
      float invd = 1.0f / diag[lane][lane];
      for (int p = 0; p < 64; ++p) {
        float zp = __shfl(z, p) * __shfl(invd, p);
        if (lane > p) z -= zp * diag[lane][p];
      }
      zs[row0 + lane] = z * invd;
    }
    __syncthreads();
  }
  // reductions: bv = ||z||^2, ld = sum log L_ii
  float bv = 0.0f, ld = 0.0f;
  for (int i = tid; i < Q; i += 256) {
    float zi = zs[i];
    bv += zi * zi;
    ld += logf(G[(size_t)i * Q + i]);
  }
  float bvs = block_sum256(bv, red);
  float lds = block_sum256(ld, red);
  if (tid == 0) {
    float s2e = s2e_p[0], s2b = s2b_p[0];
    float sig2 = s2e + s2b;
    float c = s2e / sig2;
    float slp = scal[0], mtm = scal[1], tw = scal[2];
    float tty = (tw - bvs) / c;          // t' y
    float mrm = (mtm - tty) / c;         // m' R^{-1} m
    float logdetR = (float)(NOBS - Q) * logf(c) + 2.0f * lds;
    out[0] = 0.5f * logdetR + 0.5f * mrm - 0.5f * mtm + 0.5f * slp;
  }
}

// ---------------------------------------------------------------------------
extern "C" void kernel_launch(void* const* d_in, const int* in_sizes, int n_in,
                              void* d_out, int out_size, void* d_ws, size_t ws_size,
                              hipStream_t stream) {
  const float* yt   = (const float*)d_in[0];
  const float* yp   = (const float*)d_in[1];
  const int*   zidx = (const int*)d_in[2];
  const float* dist = (const float*)d_in[3];
  const float* s2e  = (const float*)d_in[4];
  const float* s2b  = (const float*)d_in[5];
  const float* ell  = (const float*)d_in[6];

  float* ws  = (float*)d_ws;
  float* G   = ws;                         // Q*Q floats = 16 MB
  float* t   = ws + (size_t)Q * Q;         // Q
  int*   cnt = (int*)(t + Q);              // Q
  float* scal = t + 2 * Q;                 // 8 floats: slp, mtm, tw
  float* w   = scal + 8;                   // Q
  float* b   = w + Q;                      // Q

  // zero accumulators: t, cnt, scal
  hipMemsetAsync(t, 0, (2 * Q + 8) * sizeof(float), stream);

  obs_kernel<<<NOBS / 256, 256, 0, stream>>>(yt, yp, zidx, s2e, s2b, t, cnt, scal);
  build_G<<<(Q * Q) / 256, 256, 0, stream>>>(dist, s2e, s2b, ell, cnt, G);
  matvec_kernel<<<Q, 256, 0, stream>>>(dist, s2e, s2b, ell, cnt, t, w, b, scal);

  for (int s = 0; s < NSTEPS; ++s) {
    int j0 = s * NB;
    chol_diag<<<1, 64, 0, stream>>>(G, j0);
    int nb = NSTEPS - 1 - s;
    if (nb > 0) {
      chol_trsm<<<nb * 16, 256, 0, stream>>>(G, j0);
      chol_syrk<<<dim3(nb, nb), 256, 0, stream>>>(G, j0);
    }
  }

  trsv_final<<<1, 256, 0, stream>>>(G, b, scal, s2e, s2b, (float*)d_out);
}